// Round 5
// baseline (992.940 us; speedup 1.0000x reference)
//
#include <hip/hip_runtime.h>
#include <hip/hip_bf16.h>

#define NN 89250
#define NE 899756
#define INF_ 500
#define HID 256
#define NCLS 7

typedef __attribute__((ext_vector_type(8))) short bf16x8;
typedef __attribute__((ext_vector_type(4))) float f32x4;

#define GL2LDS16(gp, lp)                                                        \
    __builtin_amdgcn_global_load_lds(                                           \
        (const __attribute__((address_space(1))) void*)(gp),                    \
        (__attribute__((address_space(3))) void*)(lp), 16, 0, 0)

static __device__ __forceinline__ float b2f(short s) {
    union { unsigned int u; float f; } v;
    v.u = ((unsigned int)(unsigned short)s) << 16;
    return v.f;
}

// ---------------- CSR build ----------------
__global__ void hist_kernel(const int* __restrict__ dst, int* __restrict__ cnt, int E) {
    int e = blockIdx.x * 256 + threadIdx.x;
    if (e < E) atomicAdd(&cnt[dst[e]], 1);
}

__global__ __launch_bounds__(256) void scan1_kernel(const int* __restrict__ cnt,
                                                    int* __restrict__ loc,
                                                    int* __restrict__ bsum, int N) {
    __shared__ int sd[256];
    int b = blockIdx.x, tid = threadIdx.x;
    int base = b * 1024 + tid * 4;
    int v[4];
    int sum = 0;
#pragma unroll
    for (int k = 0; k < 4; k++) {
        int i = base + k;
        v[k] = (i < N) ? cnt[i] : 0;
        sum += v[k];
    }
    sd[tid] = sum;
    __syncthreads();
    for (int off = 1; off < 256; off <<= 1) {
        int add = (tid >= off) ? sd[tid - off] : 0;
        __syncthreads();
        sd[tid] += add;
        __syncthreads();
    }
    int run = sd[tid] - sum;
    if (tid == 255) bsum[b] = sd[255];
#pragma unroll
    for (int k = 0; k < 4; k++) {
        int i = base + k;
        if (i < N) loc[i] = run;
        run += v[k];
    }
}

__global__ __launch_bounds__(256) void scan2_kernel(int* __restrict__ bsum,
                                                    int* __restrict__ total, int nb) {
    __shared__ int sd[256];
    int tid = threadIdx.x;
    int v = (tid < nb) ? bsum[tid] : 0;
    sd[tid] = v;
    __syncthreads();
    for (int off = 1; off < 256; off <<= 1) {
        int add = (tid >= off) ? sd[tid - off] : 0;
        __syncthreads();
        sd[tid] += add;
        __syncthreads();
    }
    if (tid < nb) bsum[tid] = sd[tid] - v;
    if (tid == 255) *total = sd[255];
}

__global__ void scan3_kernel(const int* __restrict__ cnt, const int* __restrict__ loc,
                             const int* __restrict__ bsum, const int* __restrict__ total,
                             int* __restrict__ offs, int* __restrict__ cursor,
                             float* __restrict__ invc, int N) {
    int i = blockIdx.x * 256 + threadIdx.x;
    if (i < N) {
        int o = loc[i] + bsum[i >> 10];
        offs[i] = o;
        cursor[i] = o;
        invc[i] = 1.0f / fmaxf((float)cnt[i], 1.0f);
    }
    if (i == 0) offs[N] = *total;
}

__global__ void scatter_kernel(const int* __restrict__ src, const int* __restrict__ dst,
                               const float* __restrict__ w, int* __restrict__ cursor,
                               int* __restrict__ csr_src, float* __restrict__ csr_w, int E) {
    int e = blockIdx.x * 256 + threadIdx.x;
    if (e < E) {
        int d = dst[e];
        int pos = atomicAdd(&cursor[d], 1);
        csr_src[pos] = src[e];
        csr_w[pos] = w[e];
    }
}

// ---------------- conversions ----------------
__global__ void conv_x_kernel(const float* __restrict__ x, __hip_bfloat16* __restrict__ xb) {
    long long idx = (long long)blockIdx.x * 256 + threadIdx.x;
    if (idx >= (long long)NN * 128) return;
    int row = (int)(idx >> 7), slot = (int)(idx & 127);
    float4 v = make_float4(0.f, 0.f, 0.f, 0.f);
    if (slot < 125) v = *(const float4*)&x[(size_t)row * 500 + slot * 4];
    __hip_bfloat16* o = xb + (size_t)row * 512 + slot * 4;
    o[0] = __float2bfloat16(v.x);
    o[1] = __float2bfloat16(v.y);
    o[2] = __float2bfloat16(v.z);
    o[3] = __float2bfloat16(v.w);
}

__global__ void conv_w_kernel(const float* __restrict__ W, __hip_bfloat16* __restrict__ BT,
                              int K, int Kp) {
    int idx = blockIdx.x * 256 + threadIdx.x;
    if (idx >= 512 * Kp) return;
    int j = idx / Kp, k = idx - j * Kp;
    float v = (k < K) ? W[(size_t)(k + ((j >= 256) ? K : 0)) * 256 + (j & 255)] : 0.f;
    BT[idx] = __float2bfloat16(v);
}

// ---------------- MFMA GEMM ----------------
// 1D grid (multiple of 8). logical id: y = col-block fastest so the 4 blocks
// sharing an A-panel are consecutive; XCD swizzle keeps them on one XCD's L2.
__global__ __launch_bounds__(256, 2) void gemm_mfma(
    const __hip_bfloat16* __restrict__ A, const __hip_bfloat16* __restrict__ BT,
    const float* __restrict__ bias, __hip_bfloat16* __restrict__ S,
    __hip_bfloat16* __restrict__ T, int N, int K) {
    __shared__ short lA[128 * 64];
    __shared__ short lB[128 * 64];
    int tid = threadIdx.x;
    int chunk = gridDim.x >> 3;                       // nwg % 8 == 0
    int bid = blockIdx.x;
    int logical = (bid & 7) * chunk + (bid >> 3);     // bijective XCD swizzle
    int row0 = (logical >> 2) * 128;
    int col0 = (logical & 3) * 128;
    int w = tid >> 6, l = tid & 63;
    int wm = (w >> 1) * 64, wn = (w & 1) * 64;
    int lr = l & 15, lk = (l >> 4) * 8;

    const char* gA[4];
    const char* gB[4];
    int ls[4];
#pragma unroll
    for (int p = 0; p < 4; p++) {
        int s = tid + p * 256;
        int r = s >> 3, c = s & 7;
        int ga_row = row0 + r;
        if (ga_row > N - 1) ga_row = N - 1;
        gA[p] = (const char*)A + (size_t)ga_row * K * 2 + c * 16;
        gB[p] = (const char*)BT + (size_t)(col0 + r) * K * 2 + c * 16;
        ls[p] = s * 16;
    }

    f32x4 acc[4][4];
#pragma unroll
    for (int m = 0; m < 4; m++)
#pragma unroll
        for (int n = 0; n < 4; n++) acc[m][n] = (f32x4){0.f, 0.f, 0.f, 0.f};

    int KT = K >> 6;
    for (int kt = 0; kt < KT; kt++) {
        size_t koff = (size_t)kt * 128;
#pragma unroll
        for (int p = 0; p < 4; p++) GL2LDS16(gA[p] + koff, (char*)lA + ls[p]);
#pragma unroll
        for (int p = 0; p < 4; p++) GL2LDS16(gB[p] + koff, (char*)lB + ls[p]);
        __syncthreads();
#pragma unroll
        for (int kk = 0; kk < 64; kk += 32) {
            bf16x8 af[4], bfr[4];
#pragma unroll
            for (int m = 0; m < 4; m++)
                af[m] = *(const bf16x8*)&lA[(wm + m * 16 + lr) * 64 + kk + lk];
#pragma unroll
            for (int n = 0; n < 4; n++)
                bfr[n] = *(const bf16x8*)&lB[(wn + n * 16 + lr) * 64 + kk + lk];
#pragma unroll
            for (int m = 0; m < 4; m++)
#pragma unroll
                for (int n = 0; n < 4; n++)
                    acc[m][n] = __builtin_amdgcn_mfma_f32_16x16x32_bf16(af[m], bfr[n],
                                                                        acc[m][n], 0, 0, 0);
        }
        __syncthreads();
    }

    int crow_base = row0 + wm + (l >> 4) * 4;
    bool isT = (col0 >= 256);
#pragma unroll
    for (int n = 0; n < 4; n++) {
        int col = col0 + wn + n * 16 + lr;
        float bv = isT ? 0.f : bias[col];
        int ocol = col & 255;
#pragma unroll
        for (int m = 0; m < 4; m++) {
#pragma unroll
            for (int r = 0; r < 4; r++) {
                int row = crow_base + m * 16 + r;
                if (row < N) {
                    float v = acc[m][n][r] + bv;
                    if (isT)
                        T[(size_t)row * 256 + ocol] = __float2bfloat16(v);
                    else
                        S[(size_t)row * 256 + ocol] = __float2bfloat16(v);
                }
            }
        }
    }
}

// ---------------- fused aggregate + relu + logits partial ----------------
__global__ __launch_bounds__(256) void agg_fused_kernel(
    const __hip_bfloat16* __restrict__ S, const __hip_bfloat16* __restrict__ T,
    const int* __restrict__ offs, const int* __restrict__ csr_src,
    const float* __restrict__ csr_w, const float* __restrict__ invc,
    const float* __restrict__ Wlc, __hip_bfloat16* __restrict__ act,
    float* __restrict__ logits, int N) {
    __shared__ float sW[HID * NCLS];
    for (int i = threadIdx.x; i < HID * NCLS; i += 256) sW[i] = Wlc[i];
    __syncthreads();

    int g = threadIdx.x >> 5, t = threadIdx.x & 31;
    int n = blockIdx.x * 8 + g;
    if (n >= N) return;
    int beg = offs[n], end = offs[n + 1];

    float acc[8] = {};
    int j = beg;
    for (; j + 8 <= end; j += 8) {
        int ss[8];
        float ww[8];
#pragma unroll
        for (int u = 0; u < 8; u++) {
            ss[u] = csr_src[j + u];
            ww[u] = csr_w[j + u];
        }
        bf16x8 rr[8];
#pragma unroll
        for (int u = 0; u < 8; u++) rr[u] = *(const bf16x8*)&T[(size_t)ss[u] * 256 + t * 8];
#pragma unroll
        for (int u = 0; u < 8; u++)
#pragma unroll
            for (int k = 0; k < 8; k++) acc[k] += b2f(rr[u][k]) * ww[u];
    }
    for (; j < end; j++) {
        int s0 = csr_src[j];
        float w0 = csr_w[j];
        bf16x8 r0 = *(const bf16x8*)&T[(size_t)s0 * 256 + t * 8];
#pragma unroll
        for (int k = 0; k < 8; k++) acc[k] += b2f(r0[k]) * w0;
    }

    float ic = invc[n];
    bf16x8 sv = *(const bf16x8*)&S[(size_t)n * 256 + t * 8];
    float a[8];
#pragma unroll
    for (int k = 0; k < 8; k++) a[k] = fmaxf(b2f(sv[k]) + acc[k] * ic, 0.f);

    bf16x8 ov;
#pragma unroll
    for (int k = 0; k < 8; k++) {
        __hip_bfloat16 h = __float2bfloat16(a[k]);
        ov[k] = *reinterpret_cast<short*>(&h);
    }
    *(bf16x8*)&act[(size_t)n * 256 + t * 8] = ov;

    float pl[NCLS] = {};
#pragma unroll
    for (int k = 0; k < 8; k++) {
        int f = t * 8 + k;
        float av = a[k];
#pragma unroll
        for (int c = 0; c < NCLS; c++) pl[c] += av * sW[f * NCLS + c];
    }
#pragma unroll
    for (int c = 0; c < NCLS; c++) {
#pragma unroll
        for (int off = 16; off >= 1; off >>= 1) pl[c] += __shfl_xor(pl[c], off, 32);
    }
    if (t == 0) {
        float* lp = logits + (size_t)n * NCLS;
#pragma unroll
        for (int c = 0; c < NCLS; c++) lp[c] += pl[c];
    }
}

// ---------------- final log_softmax ----------------
__global__ void logsoftmax_kernel(const float* __restrict__ logits, const float* __restrict__ bl,
                                  float* __restrict__ out, int N) {
    int n = blockIdx.x * 256 + threadIdx.x;
    if (n >= N) return;
    float l[NCLS];
    float m = -1e30f;
#pragma unroll
    for (int c = 0; c < NCLS; c++) {
        l[c] = logits[(size_t)n * NCLS + c] + bl[c];
        m = fmaxf(m, l[c]);
    }
    float s = 0.f;
#pragma unroll
    for (int c = 0; c < NCLS; c++) s += expf(l[c] - m);
    float lse = m + logf(s);
#pragma unroll
    for (int c = 0; c < NCLS; c++) out[(size_t)n * NCLS + c] = l[c] - lse;
}

extern "C" void kernel_launch(void* const* d_in, const int* in_sizes, int n_in,
                              void* d_out, int out_size, void* d_ws, size_t ws_size,
                              hipStream_t stream) {
    const float* x  = (const float*)d_in[0];
    const int*   ei = (const int*)d_in[1];
    const float* ew = (const float*)d_in[2];
    const float* W1 = (const float*)d_in[3];
    const float* b1 = (const float*)d_in[4];
    const float* W2 = (const float*)d_in[5];
    const float* b2 = (const float*)d_in[6];
    const float* W3 = (const float*)d_in[7];
    const float* b3 = (const float*)d_in[8];
    const float* Wl = (const float*)d_in[9];
    const float* bl = (const float*)d_in[10];
    float* out = (float*)d_out;

    const int N = NN, E = NE;
    const int* src = ei;
    const int* dst = ei + E;

    char* p = (char*)d_ws;
    auto alloc = [&](size_t bytes) {
        void* r = (void*)p;
        p += (bytes + 255) & ~(size_t)255;
        return r;
    };
    __hip_bfloat16* S      = (__hip_bfloat16*)alloc((size_t)N * 256 * 2);
    __hip_bfloat16* T      = (__hip_bfloat16*)alloc((size_t)N * 256 * 2);
    __hip_bfloat16* act    = (__hip_bfloat16*)alloc((size_t)N * 256 * 2);
    __hip_bfloat16* xbf    = (__hip_bfloat16*)alloc((size_t)N * 512 * 2);
    __hip_bfloat16* B1T    = (__hip_bfloat16*)alloc((size_t)512 * 512 * 2);
    __hip_bfloat16* B2T    = (__hip_bfloat16*)alloc((size_t)512 * 256 * 2);
    __hip_bfloat16* B3T    = (__hip_bfloat16*)alloc((size_t)512 * 256 * 2);
    float*          logits = (float*)alloc((size_t)N * NCLS * 4);
    int*            cnt    = (int*)alloc((size_t)N * 4);
    int*            offs   = (int*)alloc((size_t)(N + 1) * 4);
    int*            cursor = (int*)alloc((size_t)N * 4);
    float*          invc   = (float*)alloc((size_t)N * 4);
    int*            loc    = (int*)alloc((size_t)N * 4);
    int*            bsum   = (int*)alloc(256 * 4);
    int*            total  = (int*)alloc(4);
    int*            csr_src = (int*)alloc((size_t)E * 4);
    float*          csr_w   = (float*)alloc((size_t)E * 4);

    hipMemsetAsync(cnt, 0, (size_t)N * 4, stream);
    hipMemsetAsync(logits, 0, (size_t)N * NCLS * 4, stream);

    // CSR build
    int nb = (N + 1023) / 1024;
    hist_kernel<<<(E + 255) / 256, 256, 0, stream>>>(dst, cnt, E);
    scan1_kernel<<<nb, 256, 0, stream>>>(cnt, loc, bsum, N);
    scan2_kernel<<<1, 256, 0, stream>>>(bsum, total, nb);
    scan3_kernel<<<(N + 255) / 256, 256, 0, stream>>>(cnt, loc, bsum, total, offs, cursor, invc, N);
    scatter_kernel<<<(E + 255) / 256, 256, 0, stream>>>(src, dst, ew, cursor, csr_src, csr_w, E);

    // conversions
    conv_x_kernel<<<(int)(((long long)N * 128 + 255) / 256), 256, 0, stream>>>(x, xbf);
    conv_w_kernel<<<(512 * 512 + 255) / 256, 256, 0, stream>>>(W1, B1T, INF_, 512);
    conv_w_kernel<<<(512 * 256 + 255) / 256, 256, 0, stream>>>(W2, B2T, HID, 256);
    conv_w_kernel<<<(512 * 256 + 255) / 256, 256, 0, stream>>>(W3, B3T, HID, 256);

    int nwg = ((N + 127) / 128) * 4;  // 698*4 = 2792, multiple of 8
    int agrid = (N + 7) / 8;

    // layer 1
    gemm_mfma<<<nwg, 256, 0, stream>>>(xbf, B1T, b1, S, T, N, 512);
    agg_fused_kernel<<<agrid, 256, 0, stream>>>(S, T, offs, csr_src, csr_w, invc,
                                                Wl, act, logits, N);
    // layer 2
    gemm_mfma<<<nwg, 256, 0, stream>>>(act, B2T, b2, S, T, N, 256);
    agg_fused_kernel<<<agrid, 256, 0, stream>>>(S, T, offs, csr_src, csr_w, invc,
                                                Wl + (size_t)HID * NCLS, act, logits, N);
    // layer 3
    gemm_mfma<<<nwg, 256, 0, stream>>>(act, B3T, b3, S, T, N, 256);
    agg_fused_kernel<<<agrid, 256, 0, stream>>>(S, T, offs, csr_src, csr_w, invc,
                                                Wl + (size_t)2 * HID * NCLS, act, logits, N);

    logsoftmax_kernel<<<(N + 255) / 256, 256, 0, stream>>>(logits, bl, out, N);
}